// Round 7
// baseline (239.008 us; speedup 1.0000x reference)
//
#include <hip/hip_runtime.h>

// Xonv2D: location-dependent 3x3 conv.
//   x:       (B=4, CIN=16, H=128, W=128)  fp32
//   weights: (H, W, COUT=16, CIN=16, 3, 3) fp32   -- 151 MB, the traffic driver
//   bias:    (H, W, COUT) fp32
//   out:     (B, COUT, H, W) fp32
//
// V6 = V5 + cross-site software pipelining. V5 (kernel ~50us) left ~2x on the
// table vs the ~24us HBM floor: each one-shot wave exposed ~900 cyc of HBM
// latency (fetch -> vmcnt wait -> ds_write) on its critical path. Now each
// wave runs 4 consecutive sites, prefetching site i+1's 9 coalesced weight
// float4s into registers WHILE computing site i -- steady-state fetch latency
// hides behind transpose+compute. Single 9 KB LDS slice per wave reused
// across sites (per-wave DS ordering + compiler lgkmcnt handles WAR; no
// barrier). 4096 waves, 1024 blocks, 16 waves/CU.
//
// Kept from v5: coalesced wave-contiguous weight fetch (lane l takes f4
// j*64+l), wave-local LDS transpose to (o,g) fragments, x window rows as
// dword-aligned float4 (w<=125 fast path), wave-uniform border path, XCD
// banding, butterfly reduce + single 64-lane store.

#define HWD  128
#define CIND 16
#define COUTD 16
#define BATCH 4
#define KSITES 4

typedef float f4  __attribute__((ext_vector_type(4)));
typedef float f4u __attribute__((ext_vector_type(4), aligned(4)));

__global__ __launch_bounds__(256) void xonv2d_kernel(
    const float* __restrict__ x,
    const float* __restrict__ wts,
    const float* __restrict__ bias,
    float* __restrict__ out)
{
    __shared__ f4 wsm[4][576];   // 4 waves x 9216 B

    const int lane = threadIdx.x & 63;
    const int wave = threadIdx.x >> 6;

    // XCD banding: 1024 blocks; XCD k = blockIdx%8 owns sites [k*2048,(k+1)*2048).
    // Each wave owns 4 consecutive sites (same row: 32 waves cover a 128-row).
    const int xcd = blockIdx.x & 7;
    const int idx = blockIdx.x >> 3;          // 0..127
    const int base = xcd * 2048 + idx * 16 + wave * 4;

    const int o = lane & 15;    // output channel
    const int g = lane >> 4;    // channel group: c in [4g, 4g+4)
    const int c0 = g * 4;

    // ---- prefetch site 0's weights (coalesced: lane l takes f4 j*64+l) ----
    f4 st[9];
    {
        const f4* gw = (const f4*)wts + (size_t)base * 576;
        #pragma unroll
        for (int j = 0; j < 9; ++j)
            st[j] = __builtin_nontemporal_load(gw + j * 64 + lane);
    }

    for (int i = 0; i < KSITES; ++i) {
        const int site = base + i;
        const int h = site >> 7;
        const int w = site & 127;

        // ---- stage current site's weights into LDS (waits on st's vmcnt) ----
        #pragma unroll
        for (int j = 0; j < 9; ++j)
            wsm[wave][j * 64 + lane] = st[j];            // ds_write_b128

        f4 wv[9];
        {
            const f4* lp = &wsm[wave][o * 36 + g * 9];
            #pragma unroll
            for (int j = 0; j < 9; ++j) wv[j] = lp[j];   // ds_read_b128
        }
        const float* wf = (const float*)wv;

        // ---- prefetch NEXT site's weights (overlaps compute below) ----
        if (i + 1 < KSITES) {
            const f4* gw = (const f4*)wts + (size_t)(site + 1) * 576;
            #pragma unroll
            for (int j = 0; j < 9; ++j)
                st[j] = __builtin_nontemporal_load(gw + j * 64 + lane);
        }

        const float bv = bias[(size_t)site * COUTD + o];

        float acc[BATCH] = {0.f, 0.f, 0.f, 0.f};

        // w <= 125: float4 row loads read columns w-1..w+2 <= 127, in-bounds.
        const bool interior = (h >= 1) & (h <= HWD - 2) & (w >= 1) & (w <= HWD - 3);

        if (interior) {
            #pragma unroll
            for (int cc = 0; cc < 4; ++cc) {
                #pragma unroll
                for (int b = 0; b < BATCH; ++b) {
                    const float* xb = x + (((size_t)(b * CIND + c0 + cc) * HWD + (h - 1)) * HWD) + (w - 1);
                    f4 r0 = *(const f4u*)(xb);
                    f4 r1 = *(const f4u*)(xb + HWD);
                    f4 r2 = *(const f4u*)(xb + 2 * HWD);
                    const float* wr = wf + cc * 9;
                    acc[b] = fmaf(r0.x, wr[0], acc[b]);
                    acc[b] = fmaf(r0.y, wr[1], acc[b]);
                    acc[b] = fmaf(r0.z, wr[2], acc[b]);
                    acc[b] = fmaf(r1.x, wr[3], acc[b]);
                    acc[b] = fmaf(r1.y, wr[4], acc[b]);
                    acc[b] = fmaf(r1.z, wr[5], acc[b]);
                    acc[b] = fmaf(r2.x, wr[6], acc[b]);
                    acc[b] = fmaf(r2.y, wr[7], acc[b]);
                    acc[b] = fmaf(r2.z, wr[8], acc[b]);
                }
            }
        } else {
            #pragma unroll
            for (int cc = 0; cc < 4; ++cc) {
                #pragma unroll
                for (int b = 0; b < BATCH; ++b) {
                    const float* xb = x + ((size_t)(b * CIND + c0 + cc)) * (HWD * HWD);
                    #pragma unroll
                    for (int kh = 0; kh < 3; ++kh) {
                        const int hy = h + kh - 1;
                        #pragma unroll
                        for (int kw = 0; kw < 3; ++kw) {
                            const int wx = w + kw - 1;
                            const bool ok = (hy >= 0) & (hy < HWD) & (wx >= 0) & (wx < HWD);
                            const float xv = ok ? xb[hy * HWD + wx] : 0.f;
                            acc[b] = fmaf(xv, wf[cc * 9 + kh * 3 + kw], acc[b]);
                        }
                    }
                }
            }
        }

        // ---- butterfly reduce over the 4 c-groups ----
        float r[BATCH];
        #pragma unroll
        for (int b = 0; b < BATCH; ++b) {
            float v = acc[b];
            v += __shfl_xor(v, 32);
            v += __shfl_xor(v, 16);
            r[b] = v;
        }

        // lane (g,o) stores batch b = g: one store, all 64 lanes active
        const float vout = (g == 0) ? r[0] : (g == 1) ? r[1] : (g == 2) ? r[2] : r[3];
        out[((size_t)(g * COUTD + o)) * (HWD * HWD) + h * HWD + w] = vout + bv;
    }
}

extern "C" void kernel_launch(void* const* d_in, const int* in_sizes, int n_in,
                              void* d_out, int out_size, void* d_ws, size_t ws_size,
                              hipStream_t stream) {
    const float* x    = (const float*)d_in[0];
    const float* wts  = (const float*)d_in[1];
    const float* bias = (const float*)d_in[2];
    float* out = (float*)d_out;

    // 16384 sites / 4 per wave = 4096 waves; 4 waves per 256-thread block.
    const int blocks = (HWD * HWD) / (4 * KSITES);
    xonv2d_kernel<<<blocks, 256, 0, stream>>>(x, wts, bias, out);
}

// Round 8
// 238.024 us; speedup vs baseline: 1.0041x; 1.0041x over previous
//
#include <hip/hip_runtime.h>

// Xonv2D: location-dependent 3x3 conv.
//   x:       (B=4, CIN=16, H=128, W=128)  fp32
//   weights: (H, W, COUT=16, CIN=16, 3, 3) fp32   -- 151 MB, the traffic driver
//   bias:    (H, W, COUT) fp32
//   out:     (B, COUT, H, W) fp32
//
// V7: double-buffered direct-to-LDS weight pipeline (no barrier, no VGPR
// staging). v5 plateaued at ~50us (4.9 B/cyc/CU = half of m13's 10.2): each
// one-shot wave had its 9KB fetch in flight only ~1/3 of its lifetime. v6's
// register prefetch bought ILP by spending VGPRs+TLP and regressed. Now each
// wave owns 8 consecutive sites and 2 x 9KB LDS slices: at the top of site i
// it issues site i+1's 9 global_load_lds DMAs (16B/lane, coalesced 1KB/instr)
// into the other slice, then waits vmcnt(9) -- in-order vmcnt retirement
// means "all but the 9 just-issued" == current slice is complete. The next
// site's fetch is in flight across the ENTIRE compute of the current site.
// Producer wave == consumer wave -> no __syncthreads (v2's mistake).
// 72KB LDS/block -> 2 blocks/CU, 8 waves/CU; 512 blocks fill 256 CUs.
//
// Kept: wave-local LDS transpose to (o,g) fragments, x window rows as
// dword-aligned float4 (w<=125 fast path, OOB-safe), wave-uniform border
// path, XCD banding, butterfly reduce + single 64-lane store.

#define HWD  128
#define CIND 16
#define COUTD 16
#define BATCH 4
#define KSITES 8

typedef float f4  __attribute__((ext_vector_type(4)));
typedef float f4u __attribute__((ext_vector_type(4), aligned(4)));

typedef __attribute__((address_space(3))) void       lds_void_t;
typedef const __attribute__((address_space(1))) void glb_void_t;

__global__ __launch_bounds__(256) void xonv2d_kernel(
    const float* __restrict__ x,
    const float* __restrict__ wts,
    const float* __restrict__ bias,
    float* __restrict__ out)
{
    __shared__ f4 wsm[4][2][576];   // 4 waves x 2 slices x 9216 B = 72 KB

    const int lane = threadIdx.x & 63;
    const int wave = threadIdx.x >> 6;

    // XCD banding: XCD k = blockIdx%8 owns sites [k*2048,(k+1)*2048).
    // 512 blocks; each wave owns 8 consecutive sites (row-aligned: 8 | base).
    const int xcd = blockIdx.x & 7;
    const int idx = blockIdx.x >> 3;              // 0..63
    const int base = xcd * 2048 + idx * 32 + wave * 8;

    const int o = lane & 15;    // output channel
    const int g = lane >> 4;    // channel group: c in [4g, 4g+4)
    const int c0 = g * 4;

    // ---- preloop: DMA site base's 9216B -> slice 0 (lane l gets f4 j*64+l) ----
    {
        const f4* gw = (const f4*)wts + (size_t)base * 576 + lane;
        #pragma unroll
        for (int j = 0; j < 9; ++j)
            __builtin_amdgcn_global_load_lds((glb_void_t*)(gw + j * 64),
                                             (lds_void_t*)(&wsm[wave][0][j * 64]),
                                             16, 0, 0);
    }

    for (int i = 0; i < KSITES; ++i) {
        const int site = base + i;
        const int h = site >> 7;
        const int w = site & 127;
        const int cur = i & 1;

        // ---- issue NEXT site's DMA into the other slice, then wait current ----
        if (i + 1 < KSITES) {
            const f4* gw = (const f4*)wts + (size_t)(site + 1) * 576 + lane;
            #pragma unroll
            for (int j = 0; j < 9; ++j)
                __builtin_amdgcn_global_load_lds((glb_void_t*)(gw + j * 64),
                                                 (lds_void_t*)(&wsm[wave][cur ^ 1][j * 64]),
                                                 16, 0, 0);
            // vmcnt(9): all but the 9 just-issued DMAs retired (in-order) ->
            // current slice is fully in LDS. lgkmcnt=15/expcnt=7 = don't-care.
            __builtin_amdgcn_s_waitcnt(0xF79);
        } else {
            // last site: its DMAs were provably drained by the previous
            // iteration's x-load waits; vmcnt(1) allows a straggling store.
            __builtin_amdgcn_s_waitcnt(0xF71);
        }

        // ---- per-lane (o,g) 36-float fragment from current slice ----
        f4 wv[9];
        {
            const f4* lp = &wsm[wave][cur][o * 36 + g * 9];
            #pragma unroll
            for (int j = 0; j < 9; ++j) wv[j] = lp[j];   // ds_read_b128
        }
        const float* wf = (const float*)wv;

        const float bv = bias[(size_t)site * COUTD + o];

        float acc[BATCH] = {0.f, 0.f, 0.f, 0.f};

        // w <= 125: float4 row loads read columns w-1..w+2 <= 127, in-bounds.
        const bool interior = (h >= 1) & (h <= HWD - 2) & (w >= 1) & (w <= HWD - 3);

        if (interior) {
            #pragma unroll
            for (int cc = 0; cc < 4; ++cc) {
                #pragma unroll
                for (int b = 0; b < BATCH; ++b) {
                    const float* xb = x + (((size_t)(b * CIND + c0 + cc) * HWD + (h - 1)) * HWD) + (w - 1);
                    f4 r0 = *(const f4u*)(xb);
                    f4 r1 = *(const f4u*)(xb + HWD);
                    f4 r2 = *(const f4u*)(xb + 2 * HWD);
                    const float* wr = wf + cc * 9;
                    acc[b] = fmaf(r0.x, wr[0], acc[b]);
                    acc[b] = fmaf(r0.y, wr[1], acc[b]);
                    acc[b] = fmaf(r0.z, wr[2], acc[b]);
                    acc[b] = fmaf(r1.x, wr[3], acc[b]);
                    acc[b] = fmaf(r1.y, wr[4], acc[b]);
                    acc[b] = fmaf(r1.z, wr[5], acc[b]);
                    acc[b] = fmaf(r2.x, wr[6], acc[b]);
                    acc[b] = fmaf(r2.y, wr[7], acc[b]);
                    acc[b] = fmaf(r2.z, wr[8], acc[b]);
                }
            }
        } else {
            #pragma unroll
            for (int cc = 0; cc < 4; ++cc) {
                #pragma unroll
                for (int b = 0; b < BATCH; ++b) {
                    const float* xb = x + ((size_t)(b * CIND + c0 + cc)) * (HWD * HWD);
                    #pragma unroll
                    for (int kh = 0; kh < 3; ++kh) {
                        const int hy = h + kh - 1;
                        #pragma unroll
                        for (int kw = 0; kw < 3; ++kw) {
                            const int wx = w + kw - 1;
                            const bool ok = (hy >= 0) & (hy < HWD) & (wx >= 0) & (wx < HWD);
                            const float xv = ok ? xb[hy * HWD + wx] : 0.f;
                            acc[b] = fmaf(xv, wf[cc * 9 + kh * 3 + kw], acc[b]);
                        }
                    }
                }
            }
        }

        // ---- butterfly reduce over the 4 c-groups ----
        float r[BATCH];
        #pragma unroll
        for (int b = 0; b < BATCH; ++b) {
            float v = acc[b];
            v += __shfl_xor(v, 32);
            v += __shfl_xor(v, 16);
            r[b] = v;
        }

        // lane (g,o) stores batch b = g: one store, all 64 lanes active
        const float vout = (g == 0) ? r[0] : (g == 1) ? r[1] : (g == 2) ? r[2] : r[3];
        out[((size_t)(g * COUTD + o)) * (HWD * HWD) + h * HWD + w] = vout + bv;
    }
}

extern "C" void kernel_launch(void* const* d_in, const int* in_sizes, int n_in,
                              void* d_out, int out_size, void* d_ws, size_t ws_size,
                              hipStream_t stream) {
    const float* x    = (const float*)d_in[0];
    const float* wts  = (const float*)d_in[1];
    const float* bias = (const float*)d_in[2];
    float* out = (float*)d_out;

    // 16384 sites / 8 per wave = 2048 waves; 4 waves per block = 512 blocks.
    const int blocks = (HWD * HWD) / (4 * KSITES);
    xonv2d_kernel<<<blocks, 256, 0, stream>>>(x, wts, bias, out);
}